// Round 1
// baseline (3316.465 us; speedup 1.0000x reference)
//
#include <hip/hip_runtime.h>
#include <hip/hip_bf16.h>

#define N_NODES 50000
#define E_EDGES 800000
#define IN_DIM  256
#define HID     128
#define FEAT_IN 266
#define EHID    64
#define NEG     0.2f
#define PRIOR_LOG (-1.0986122886681098f)  // log(1/3 + 1e-12)

// ---------------- weight transpose: W[R][C] -> WT[C][R] ----------------
__global__ void k_transpose(const float* __restrict__ W, float* __restrict__ WT, int R, int C) {
  int i = blockIdx.x * 256 + threadIdx.x;
  if (i < R * C) {
    int r = i / C, c = i - r * C;
    WT[c * R + r] = W[i];
  }
}

// ---------------- GEMM1: hx = [x | onehot(y)*mask] @ W1^T ----------------
// block = 256 thr (4 waves), 32 rows/block; lane owns cols (lane, lane+64)
__global__ __launch_bounds__(256) void k_gemm1(
    const float* __restrict__ x, const int* __restrict__ y, const int* __restrict__ mask,
    const float* __restrict__ W1T, float* __restrict__ hx) {
  __shared__ float xs[32][268];
  int b0 = blockIdx.x * 32;
  int t = threadIdx.x;
  // stage x tile: 32 rows x 256 cols, float4 coalesced
  {
    int c4 = t & 63, rb = t >> 6;  // rb 0..3
    for (int i = 0; i < 8; ++i) {
      int r = rb * 8 + i;
      int row = b0 + r;
      float4 v = make_float4(0.f, 0.f, 0.f, 0.f);
      if (row < N_NODES) v = *(const float4*)&x[(size_t)row * IN_DIM + c4 * 4];
      *(float4*)&xs[r][c4 * 4] = v;
    }
  }
  // label columns 256..267 (10 one-hot + 2 pad)
  for (int s = t; s < 32 * 12; s += 256) {
    int r = s / 12, c = s - r * 12;
    int row = b0 + r;
    float v = 0.f;
    if (c < 10 && row < N_NODES)
      v = (mask[row] != 0 && y[row] == c) ? 1.f : 0.f;
    xs[r][256 + c] = v;
  }
  __syncthreads();

  int lane = t & 63, wv = t >> 6;
  int r0 = wv * 8;
  int k0 = lane, k1 = lane + 64;
  float acc0[8], acc1[8];
#pragma unroll
  for (int i = 0; i < 8; ++i) { acc0[i] = 0.f; acc1[i] = 0.f; }

  for (int f = 0; f < 264; f += 4) {
    float wa0 = W1T[(f + 0) * HID + k0], wb0 = W1T[(f + 0) * HID + k1];
    float wa1 = W1T[(f + 1) * HID + k0], wb1 = W1T[(f + 1) * HID + k1];
    float wa2 = W1T[(f + 2) * HID + k0], wb2 = W1T[(f + 2) * HID + k1];
    float wa3 = W1T[(f + 3) * HID + k0], wb3 = W1T[(f + 3) * HID + k1];
#pragma unroll
    for (int i = 0; i < 8; ++i) {
      float4 xv = *(float4*)&xs[r0 + i][f];
      float a = acc0[i], b = acc1[i];
      a = fmaf(xv.x, wa0, a); b = fmaf(xv.x, wb0, b);
      a = fmaf(xv.y, wa1, a); b = fmaf(xv.y, wb1, b);
      a = fmaf(xv.z, wa2, a); b = fmaf(xv.z, wb2, b);
      a = fmaf(xv.w, wa3, a); b = fmaf(xv.w, wb3, b);
      acc0[i] = a; acc1[i] = b;
    }
  }
  for (int f = 264; f < 266; ++f) {
    float wa = W1T[f * HID + k0], wb = W1T[f * HID + k1];
#pragma unroll
    for (int i = 0; i < 8; ++i) {
      float xv = xs[r0 + i][f];
      acc0[i] = fmaf(xv, wa, acc0[i]);
      acc1[i] = fmaf(xv, wb, acc1[i]);
    }
  }
#pragma unroll
  for (int i = 0; i < 8; ++i) {
    int row = b0 + r0 + i;
    if (row < N_NODES) {
      hx[(size_t)row * HID + k0] = acc0[i];
      hx[(size_t)row * HID + k1] = acc1[i];
    }
  }
}

// ---------------- GEMM2: hx2 = relu(in + b1) @ W2^T ----------------
__global__ __launch_bounds__(256) void k_gemm2(
    const float* __restrict__ in, const float* __restrict__ b1,
    const float* __restrict__ W2T, float* __restrict__ hx) {
  __shared__ float xs[64][128];
  int b0 = blockIdx.x * 64;
  int t = threadIdx.x;
  {
    int c4 = t & 31, rb = t >> 5;  // rb 0..7
    for (int i = 0; i < 8; ++i) {
      int r = rb * 8 + i;
      int row = b0 + r;
      float4 v = make_float4(0.f, 0.f, 0.f, 0.f);
      if (row < N_NODES) {
        v = *(const float4*)&in[(size_t)row * HID + c4 * 4];
        float4 bb = *(const float4*)&b1[c4 * 4];
        v.x = fmaxf(v.x + bb.x, 0.f); v.y = fmaxf(v.y + bb.y, 0.f);
        v.z = fmaxf(v.z + bb.z, 0.f); v.w = fmaxf(v.w + bb.w, 0.f);
      }
      *(float4*)&xs[r][c4 * 4] = v;
    }
  }
  __syncthreads();

  int lane = t & 63, wv = t >> 6;
  int r0 = wv * 16;
  int k0 = lane, k1 = lane + 64;
  float acc0[16], acc1[16];
#pragma unroll
  for (int i = 0; i < 16; ++i) { acc0[i] = 0.f; acc1[i] = 0.f; }

  for (int f = 0; f < 128; f += 4) {
    float wa0 = W2T[(f + 0) * HID + k0], wb0 = W2T[(f + 0) * HID + k1];
    float wa1 = W2T[(f + 1) * HID + k0], wb1 = W2T[(f + 1) * HID + k1];
    float wa2 = W2T[(f + 2) * HID + k0], wb2 = W2T[(f + 2) * HID + k1];
    float wa3 = W2T[(f + 3) * HID + k0], wb3 = W2T[(f + 3) * HID + k1];
#pragma unroll
    for (int i = 0; i < 16; ++i) {
      float4 xv = *(float4*)&xs[r0 + i][f];
      float a = acc0[i], b = acc1[i];
      a = fmaf(xv.x, wa0, a); b = fmaf(xv.x, wb0, b);
      a = fmaf(xv.y, wa1, a); b = fmaf(xv.y, wb1, b);
      a = fmaf(xv.z, wa2, a); b = fmaf(xv.z, wb2, b);
      a = fmaf(xv.w, wa3, a); b = fmaf(xv.w, wb3, b);
      acc0[i] = a; acc1[i] = b;
    }
  }
#pragma unroll
  for (int i = 0; i < 16; ++i) {
    int row = b0 + r0 + i;
    if (row < N_NODES) {
      hx[(size_t)row * HID + k0] = acc0[i];
      hx[(size_t)row * HID + k1] = acc1[i];
    }
  }
}

// ---------------- alpha_s / alpha_d: row dot with attention vectors ----------------
__global__ __launch_bounds__(256) void k_alpha(
    const float* __restrict__ hx, const float* __restrict__ a_s, const float* __restrict__ a_d,
    float* __restrict__ as_, float* __restrict__ ad_) {
  int gw = (blockIdx.x * 256 + threadIdx.x) >> 6;
  int lane = threadIdx.x & 63;
  if (gw >= N_NODES) return;
  float h0 = hx[(size_t)gw * HID + lane], h1 = hx[(size_t)gw * HID + 64 + lane];
  float ps = h0 * a_s[lane] + h1 * a_s[64 + lane];
  float pd = h0 * a_d[lane] + h1 * a_d[64 + lane];
#pragma unroll
  for (int m = 32; m; m >>= 1) {
    ps += __shfl_xor(ps, m, 64);
    pd += __shfl_xor(pd, m, 64);
  }
  if (lane == 0) { as_[gw] = ps; ad_[gw] = pd; }
}

// monotone uint key for float atomicMax
__device__ __forceinline__ unsigned fkey(float f) {
  unsigned u = __float_as_uint(f);
  return (u & 0x80000000u) ? ~u : (u | 0x80000000u);
}
__device__ __forceinline__ float funkey(unsigned k) {
  return (k & 0x80000000u) ? __uint_as_float(k ^ 0x80000000u) : __uint_as_float(~k);
}

// ---------------- edge score + segment max ----------------
__global__ void k_edge_max(const int* __restrict__ ei, const float* __restrict__ as_,
                           const float* __restrict__ ad_, float* __restrict__ ebuf,
                           unsigned* __restrict__ mkey) {
  int i = blockIdx.x * 256 + threadIdx.x;
  if (i >= E_EDGES + N_NODES) return;
  int s, d;
  if (i < E_EDGES) { s = ei[i]; d = ei[E_EDGES + i]; } else { s = d = i - E_EDGES; }
  float e = as_[s] + ad_[d];
  e = e > 0.f ? e : NEG * e;
  ebuf[i] = e;
  atomicMax(&mkey[d], fkey(e));
}

// ---------------- exp(e - m) + segment sum ----------------
__global__ void k_edge_exp(const int* __restrict__ ei, float* __restrict__ ebuf,
                           const unsigned* __restrict__ mkey, float* __restrict__ denom) {
  int i = blockIdx.x * 256 + threadIdx.x;
  if (i >= E_EDGES + N_NODES) return;
  int d = (i < E_EDGES) ? ei[E_EDGES + i] : (i - E_EDGES);
  float p = expf(ebuf[i] - funkey(mkey[d]));
  ebuf[i] = p;
  atomicAdd(&denom[d], p);
}

// ---------------- weighted scatter: out[d] += coef * hx[s] (wave per edge) ----------------
__global__ __launch_bounds__(256) void k_scatter(
    const int* __restrict__ ei, const float* __restrict__ ebuf,
    const float* __restrict__ denom, const float* __restrict__ hx, float* __restrict__ out) {
  int gw = (blockIdx.x * 256 + threadIdx.x) >> 6;
  int lane = threadIdx.x & 63;
  if (gw >= E_EDGES + N_NODES) return;
  int s, d;
  if (gw < E_EDGES) { s = ei[gw]; d = ei[E_EDGES + gw]; } else { s = d = gw - E_EDGES; }
  float coef = ebuf[gw] / denom[d];
  atomicAdd(&out[(size_t)d * HID + lane], coef * hx[(size_t)s * HID + lane]);
  atomicAdd(&out[(size_t)d * HID + 64 + lane], coef * hx[(size_t)s * HID + 64 + lane]);
}

// ---------------- edge MLP + softmax + loss ----------------
// block = 128 thr (2 waves); each wave owns 16 edges; lane = hidden unit (64)
#define RT 16
__global__ __launch_bounds__(128) void k_mlp(
    const int* __restrict__ ei, const float* __restrict__ h, const float* __restrict__ b2,
    const float* __restrict__ Wm1T, const float* __restrict__ bm1,
    const float* __restrict__ Wm2, const float* __restrict__ bm2,
    float* __restrict__ logits, float* __restrict__ probs, float* __restrict__ lacc) {
  __shared__ float feat[2][RT][260];
  int t = threadIdx.x;
  int wv = t >> 6, lane = t & 63;
  int eb = (blockIdx.x * 2 + wv) * RT;

  float2 b2a = *(const float2*)&b2[2 * lane];
  for (int r = 0; r < RT; ++r) {
    int e = eb + r;
    int row = ei[e], col = ei[E_EDGES + e];
    float2 hv = *(const float2*)&h[(size_t)row * HID + 2 * lane];
    *(float2*)&feat[wv][r][2 * lane] = make_float2(hv.x + b2a.x, hv.y + b2a.y);
    float2 hc = *(const float2*)&h[(size_t)col * HID + 2 * lane];
    *(float2*)&feat[wv][r][128 + 2 * lane] = make_float2(hc.x + b2a.x, hc.y + b2a.y);
  }
  __syncthreads();

  float hid[RT];
#pragma unroll
  for (int r = 0; r < RT; ++r) hid[r] = 0.f;

  for (int fc = 0; fc < 256; fc += 32) {
    float wr[32];
#pragma unroll
    for (int fi = 0; fi < 32; ++fi) wr[fi] = Wm1T[(fc + fi) * EHID + lane];
#pragma unroll
    for (int r = 0; r < RT; ++r) {
      float a = hid[r];
#pragma unroll
      for (int fi = 0; fi < 32; fi += 4) {
        float4 xv = *(float4*)&feat[wv][r][fc + fi];
        a = fmaf(xv.x, wr[fi + 0], a);
        a = fmaf(xv.y, wr[fi + 1], a);
        a = fmaf(xv.z, wr[fi + 2], a);
        a = fmaf(xv.w, wr[fi + 3], a);
      }
      hid[r] = a;
    }
  }

  float w20 = Wm2[lane], w21 = Wm2[64 + lane], w22 = Wm2[128 + lane];
  float bm20 = bm2[0], bm21 = bm2[1], bm22 = bm2[2];
  float bh = bm1[lane];
  float klsum = 0.f, rcsum = 0.f;

  for (int r = 0; r < RT; ++r) {
    float hr = fmaxf(hid[r] + bh, 0.f);
    float v0 = hr * w20, v1 = hr * w21, v2 = hr * w22;
#pragma unroll
    for (int m = 32; m; m >>= 1) {
      v0 += __shfl_xor(v0, m, 64);
      v1 += __shfl_xor(v1, m, 64);
      v2 += __shfl_xor(v2, m, 64);
    }
    float l0 = v0 + bm20, l1 = v1 + bm21, l2 = v2 + bm22;
    float mx = fmaxf(fmaxf(l0, l1), l2);
    float x0 = expf(l0 - mx), x1 = expf(l1 - mx), x2 = expf(l2 - mx);
    float inv = 1.f / (x0 + x1 + x2);
    float p0 = x0 * inv, p1 = x1 * inv, p2 = x2 * inv;
    if (lane == r) {
      int eidx = eb + r;
      logits[(size_t)eidx * 3 + 0] = l0;
      logits[(size_t)eidx * 3 + 1] = l1;
      logits[(size_t)eidx * 3 + 2] = l2;
      probs[(size_t)eidx * 3 + 0] = p0;
      probs[(size_t)eidx * 3 + 1] = p1;
      probs[(size_t)eidx * 3 + 2] = p2;
      float lp0 = logf(fmaxf(p0, 1e-12f));
      float lp1 = logf(fmaxf(p1, 1e-12f));
      float lp2 = logf(fmaxf(p2, 1e-12f));
      klsum += p0 * (lp0 - PRIOR_LOG) + p1 * (lp1 - PRIOR_LOG) + p2 * (lp2 - PRIOR_LOG);
      rcsum += logf(fmaxf(p0 + p2, 1e-12f));
    }
  }
#pragma unroll
  for (int m = 32; m; m >>= 1) {
    klsum += __shfl_xor(klsum, m, 64);
    rcsum += __shfl_xor(rcsum, m, 64);
  }
  if (lane == 0) {
    atomicAdd(&lacc[0], klsum);
    atomicAdd(&lacc[1], rcsum);
  }
}

__global__ void k_loss(const float* __restrict__ lacc, float* __restrict__ out) {
  if (threadIdx.x == 0) out[0] = (lacc[0] - lacc[1]) * (1.f / (float)E_EDGES);
}

// ---------------- launcher ----------------
extern "C" void kernel_launch(void* const* d_in, const int* in_sizes, int n_in,
                              void* d_out, int out_size, void* d_ws, size_t ws_size,
                              hipStream_t stream) {
  const float* x      = (const float*)d_in[0];
  const int*   ei     = (const int*)d_in[1];
  const int*   y      = (const int*)d_in[2];
  const int*   mask   = (const int*)d_in[3];
  const float* W1     = (const float*)d_in[4];
  const float* a_src1 = (const float*)d_in[5];
  const float* a_dst1 = (const float*)d_in[6];
  const float* b1     = (const float*)d_in[7];
  const float* W2     = (const float*)d_in[8];
  const float* a_src2 = (const float*)d_in[9];
  const float* a_dst2 = (const float*)d_in[10];
  const float* b2     = (const float*)d_in[11];
  const float* Wm1    = (const float*)d_in[12];
  const float* bm1    = (const float*)d_in[13];
  const float* Wm2    = (const float*)d_in[14];
  const float* bm2    = (const float*)d_in[15];

  float* A     = (float*)d_ws;            // hx / hx2      [N,128]
  float* Bb    = A + 6400000;             // out1 / out2   [N,128]
  float* as_   = Bb + 6400000;            // [N]
  float* ad_   = as_ + 50000;             // [N]
  unsigned* mkey = (unsigned*)(ad_ + 50000);  // [N]
  float* denom = (float*)(mkey + 50000);  // [N]
  float* ebuf  = denom + 50000;           // [E+N]
  float* W1T   = ebuf + 850000;           // [266*128]
  float* W2T   = W1T + 34048;             // [128*128]
  float* Wm1T  = W2T + 16384;             // [256*64]
  float* lacc  = Wm1T + 16384;            // [2]

  // weight transposes (per launch; same work every call)
  k_transpose<<<(HID * FEAT_IN + 255) / 256, 256, 0, stream>>>(W1, W1T, HID, FEAT_IN);
  k_transpose<<<(HID * HID + 255) / 256, 256, 0, stream>>>(W2, W2T, HID, HID);
  k_transpose<<<(EHID * 2 * HID + 255) / 256, 256, 0, stream>>>(Wm1, Wm1T, EHID, 2 * HID);

  const int EB = (E_EDGES + N_NODES + 255) / 256;   // edge-parallel blocks

  // ---- layer 1 ----
  k_gemm1<<<(N_NODES + 31) / 32, 256, 0, stream>>>(x, y, mask, W1T, A);
  k_alpha<<<(N_NODES + 3) / 4, 256, 0, stream>>>(A, a_src1, a_dst1, as_, ad_);
  hipMemsetAsync(mkey, 0, 100000 * 4, stream);      // mkey + denom (adjacent)
  hipMemsetAsync(Bb, 0, 6400000 * 4, stream);
  hipMemsetAsync(lacc, 0, 2 * 4, stream);
  k_edge_max<<<EB, 256, 0, stream>>>(ei, as_, ad_, ebuf, mkey);
  k_edge_exp<<<EB, 256, 0, stream>>>(ei, ebuf, mkey, denom);
  k_scatter<<<(E_EDGES + N_NODES + 3) / 4, 256, 0, stream>>>(ei, ebuf, denom, A, Bb);

  // ---- layer 2 ----
  k_gemm2<<<(N_NODES + 63) / 64, 256, 0, stream>>>(Bb, b1, W2T, A);
  k_alpha<<<(N_NODES + 3) / 4, 256, 0, stream>>>(A, a_src2, a_dst2, as_, ad_);
  hipMemsetAsync(mkey, 0, 100000 * 4, stream);
  hipMemsetAsync(Bb, 0, 6400000 * 4, stream);
  k_edge_max<<<EB, 256, 0, stream>>>(ei, as_, ad_, ebuf, mkey);
  k_edge_exp<<<EB, 256, 0, stream>>>(ei, ebuf, mkey, denom);
  k_scatter<<<(E_EDGES + N_NODES + 3) / 4, 256, 0, stream>>>(ei, ebuf, denom, A, Bb);

  // ---- edge MLP + loss ----
  float* logits = (float*)d_out;
  float* probs  = logits + 2400000;
  float* lossp  = logits + 4800000;
  k_mlp<<<E_EDGES / (2 * RT), 128, 0, stream>>>(ei, Bb, b2, Wm1T, bm1, Wm2, bm2,
                                                logits, probs, lacc);
  k_loss<<<1, 64, 0, stream>>>(lacc, lossp);
}

// Round 2
// 1889.743 us; speedup vs baseline: 1.7550x; 1.7550x over previous
//
#include <hip/hip_runtime.h>
#include <hip/hip_bf16.h>

#define N_NODES 50000
#define E_EDGES 800000
#define IN_DIM  256
#define HID     128
#define FEAT_IN 266
#define EHID    64
#define NEG     0.2f
#define PRIOR_LOG (-1.0986122886681098f)  // log(1/3 + 1e-12)

typedef short bf16x8 __attribute__((ext_vector_type(8)));
typedef float f32x4 __attribute__((ext_vector_type(4)));

__device__ __forceinline__ unsigned short f2bf(float f) {
  unsigned u = __float_as_uint(f);
  u += 0x7fffu + ((u >> 16) & 1u);   // round-to-nearest-even
  return (unsigned short)(u >> 16);
}

// ---------------- weight transpose: W[R][C] -> WT[C][R] ----------------
__global__ void k_transpose(const float* __restrict__ W, float* __restrict__ WT, int R, int C) {
  int i = blockIdx.x * 256 + threadIdx.x;
  if (i < R * C) {
    int r = i / C, c = i - r * C;
    WT[c * R + r] = W[i];
  }
}

// ---------------- GEMM1: hx = [x | onehot(y)*mask] @ W1^T ----------------
__global__ __launch_bounds__(256) void k_gemm1(
    const float* __restrict__ x, const int* __restrict__ y, const int* __restrict__ mask,
    const float* __restrict__ W1T, float* __restrict__ hx) {
  __shared__ float xs[32][268];
  int b0 = blockIdx.x * 32;
  int t = threadIdx.x;
  {
    int c4 = t & 63, rb = t >> 6;
    for (int i = 0; i < 8; ++i) {
      int r = rb * 8 + i;
      int row = b0 + r;
      float4 v = make_float4(0.f, 0.f, 0.f, 0.f);
      if (row < N_NODES) v = *(const float4*)&x[(size_t)row * IN_DIM + c4 * 4];
      *(float4*)&xs[r][c4 * 4] = v;
    }
  }
  for (int s = t; s < 32 * 12; s += 256) {
    int r = s / 12, c = s - r * 12;
    int row = b0 + r;
    float v = 0.f;
    if (c < 10 && row < N_NODES)
      v = (mask[row] != 0 && y[row] == c) ? 1.f : 0.f;
    xs[r][256 + c] = v;
  }
  __syncthreads();

  int lane = t & 63, wv = t >> 6;
  int r0 = wv * 8;
  int k0 = lane, k1 = lane + 64;
  float acc0[8], acc1[8];
#pragma unroll
  for (int i = 0; i < 8; ++i) { acc0[i] = 0.f; acc1[i] = 0.f; }

  for (int f = 0; f < 264; f += 4) {
    float wa0 = W1T[(f + 0) * HID + k0], wb0 = W1T[(f + 0) * HID + k1];
    float wa1 = W1T[(f + 1) * HID + k0], wb1 = W1T[(f + 1) * HID + k1];
    float wa2 = W1T[(f + 2) * HID + k0], wb2 = W1T[(f + 2) * HID + k1];
    float wa3 = W1T[(f + 3) * HID + k0], wb3 = W1T[(f + 3) * HID + k1];
#pragma unroll
    for (int i = 0; i < 8; ++i) {
      float4 xv = *(float4*)&xs[r0 + i][f];
      float a = acc0[i], b = acc1[i];
      a = fmaf(xv.x, wa0, a); b = fmaf(xv.x, wb0, b);
      a = fmaf(xv.y, wa1, a); b = fmaf(xv.y, wb1, b);
      a = fmaf(xv.z, wa2, a); b = fmaf(xv.z, wb2, b);
      a = fmaf(xv.w, wa3, a); b = fmaf(xv.w, wb3, b);
      acc0[i] = a; acc1[i] = b;
    }
  }
  for (int f = 264; f < 266; ++f) {
    float wa = W1T[f * HID + k0], wb = W1T[f * HID + k1];
#pragma unroll
    for (int i = 0; i < 8; ++i) {
      float xv = xs[r0 + i][f];
      acc0[i] = fmaf(xv, wa, acc0[i]);
      acc1[i] = fmaf(xv, wb, acc1[i]);
    }
  }
#pragma unroll
  for (int i = 0; i < 8; ++i) {
    int row = b0 + r0 + i;
    if (row < N_NODES) {
      hx[(size_t)row * HID + k0] = acc0[i];
      hx[(size_t)row * HID + k1] = acc1[i];
    }
  }
}

// ---------------- GEMM2: hx2 = relu(in + b1) @ W2^T ----------------
__global__ __launch_bounds__(256) void k_gemm2(
    const float* __restrict__ in, const float* __restrict__ b1,
    const float* __restrict__ W2T, float* __restrict__ hx) {
  __shared__ float xs[64][128];
  int b0 = blockIdx.x * 64;
  int t = threadIdx.x;
  {
    int c4 = t & 31, rb = t >> 5;
    for (int i = 0; i < 8; ++i) {
      int r = rb * 8 + i;
      int row = b0 + r;
      float4 v = make_float4(0.f, 0.f, 0.f, 0.f);
      if (row < N_NODES) {
        v = *(const float4*)&in[(size_t)row * HID + c4 * 4];
        float4 bb = *(const float4*)&b1[c4 * 4];
        v.x = fmaxf(v.x + bb.x, 0.f); v.y = fmaxf(v.y + bb.y, 0.f);
        v.z = fmaxf(v.z + bb.z, 0.f); v.w = fmaxf(v.w + bb.w, 0.f);
      }
      *(float4*)&xs[r][c4 * 4] = v;
    }
  }
  __syncthreads();

  int lane = t & 63, wv = t >> 6;
  int r0 = wv * 16;
  int k0 = lane, k1 = lane + 64;
  float acc0[16], acc1[16];
#pragma unroll
  for (int i = 0; i < 16; ++i) { acc0[i] = 0.f; acc1[i] = 0.f; }

  for (int f = 0; f < 128; f += 4) {
    float wa0 = W2T[(f + 0) * HID + k0], wb0 = W2T[(f + 0) * HID + k1];
    float wa1 = W2T[(f + 1) * HID + k0], wb1 = W2T[(f + 1) * HID + k1];
    float wa2 = W2T[(f + 2) * HID + k0], wb2 = W2T[(f + 2) * HID + k1];
    float wa3 = W2T[(f + 3) * HID + k0], wb3 = W2T[(f + 3) * HID + k1];
#pragma unroll
    for (int i = 0; i < 16; ++i) {
      float4 xv = *(float4*)&xs[r0 + i][f];
      float a = acc0[i], b = acc1[i];
      a = fmaf(xv.x, wa0, a); b = fmaf(xv.x, wb0, b);
      a = fmaf(xv.y, wa1, a); b = fmaf(xv.y, wb1, b);
      a = fmaf(xv.z, wa2, a); b = fmaf(xv.z, wb2, b);
      a = fmaf(xv.w, wa3, a); b = fmaf(xv.w, wb3, b);
      acc0[i] = a; acc1[i] = b;
    }
  }
#pragma unroll
  for (int i = 0; i < 16; ++i) {
    int row = b0 + r0 + i;
    if (row < N_NODES) {
      hx[(size_t)row * HID + k0] = acc0[i];
      hx[(size_t)row * HID + k1] = acc1[i];
    }
  }
}

// ---------------- alpha_s / alpha_d ----------------
__global__ __launch_bounds__(256) void k_alpha(
    const float* __restrict__ hx, const float* __restrict__ a_s, const float* __restrict__ a_d,
    float* __restrict__ as_, float* __restrict__ ad_) {
  int gw = (blockIdx.x * 256 + threadIdx.x) >> 6;
  int lane = threadIdx.x & 63;
  if (gw >= N_NODES) return;
  float h0 = hx[(size_t)gw * HID + lane], h1 = hx[(size_t)gw * HID + 64 + lane];
  float ps = h0 * a_s[lane] + h1 * a_s[64 + lane];
  float pd = h0 * a_d[lane] + h1 * a_d[64 + lane];
#pragma unroll
  for (int m = 32; m; m >>= 1) {
    ps += __shfl_xor(ps, m, 64);
    pd += __shfl_xor(pd, m, 64);
  }
  if (lane == 0) { as_[gw] = ps; ad_[gw] = pd; }
}

__device__ __forceinline__ unsigned fkey(float f) {
  unsigned u = __float_as_uint(f);
  return (u & 0x80000000u) ? ~u : (u | 0x80000000u);
}
__device__ __forceinline__ float funkey(unsigned k) {
  return (k & 0x80000000u) ? __uint_as_float(k ^ 0x80000000u) : __uint_as_float(~k);
}

// ---------------- edge score + segment max ----------------
__global__ void k_edge_max(const int* __restrict__ ei, const float* __restrict__ as_,
                           const float* __restrict__ ad_, float* __restrict__ ebuf,
                           unsigned* __restrict__ mkey) {
  int i = blockIdx.x * 256 + threadIdx.x;
  if (i >= E_EDGES + N_NODES) return;
  int s, d;
  if (i < E_EDGES) { s = ei[i]; d = ei[E_EDGES + i]; } else { s = d = i - E_EDGES; }
  float e = as_[s] + ad_[d];
  e = e > 0.f ? e : NEG * e;
  ebuf[i] = e;
  atomicMax(&mkey[d], fkey(e));
}

// ---------------- exp(e - m) + segment sum ----------------
__global__ void k_edge_exp(const int* __restrict__ ei, float* __restrict__ ebuf,
                           const unsigned* __restrict__ mkey, float* __restrict__ denom) {
  int i = blockIdx.x * 256 + threadIdx.x;
  if (i >= E_EDGES + N_NODES) return;
  int d = (i < E_EDGES) ? ei[E_EDGES + i] : (i - E_EDGES);
  float p = expf(ebuf[i] - funkey(mkey[d]));
  ebuf[i] = p;
  atomicAdd(&denom[d], p);
}

// ---------------- weighted scatter ----------------
__global__ __launch_bounds__(256) void k_scatter(
    const int* __restrict__ ei, const float* __restrict__ ebuf,
    const float* __restrict__ denom, const float* __restrict__ hx, float* __restrict__ out) {
  int gw = (blockIdx.x * 256 + threadIdx.x) >> 6;
  int lane = threadIdx.x & 63;
  if (gw >= E_EDGES + N_NODES) return;
  int s, d;
  if (gw < E_EDGES) { s = ei[gw]; d = ei[E_EDGES + gw]; } else { s = d = gw - E_EDGES; }
  float coef = ebuf[gw] / denom[d];
  atomicAdd(&out[(size_t)d * HID + lane], coef * hx[(size_t)s * HID + lane]);
  atomicAdd(&out[(size_t)d * HID + 64 + lane], coef * hx[(size_t)s * HID + 64 + lane]);
}

// ---------------- fill Bb rows with b2 (so scatter output = h + b2) ----------------
__global__ void k_fillb2(const float* __restrict__ b2, float* __restrict__ out) {
  int i = blockIdx.x * 256 + threadIdx.x;
  if (i < N_NODES * HID) out[i] = b2[i & 127];
}

// ---------------- fp32 -> bf16 conversions ----------------
__global__ void k_tobf16(const float* __restrict__ in, unsigned short* __restrict__ out) {
  int i = blockIdx.x * 256 + threadIdx.x;
  if (i < N_NODES * HID) out[i] = f2bf(in[i]);
}
__global__ void k_cvtw(const float* __restrict__ in, unsigned short* __restrict__ out, int n) {
  int i = blockIdx.x * 256 + threadIdx.x;
  if (i < n) out[i] = f2bf(in[i]);
}

// ---------------- edge MLP via bf16 MFMA + fused softmax + loss ----------------
// 256 thr = 4 waves; block = 128 edges; wave = 32 edges (two 16-row MFMA tiles)
// feat LDS: 128 rows x 512B ([h_bf16[src] | h_bf16[dst]]), XOR-swizzled (row&7)<<4
__global__ __launch_bounds__(256) void k_mlp_mfma(
    const int* __restrict__ ei, const unsigned short* __restrict__ hb,
    const unsigned short* __restrict__ wb, const float* __restrict__ bm1,
    const float* __restrict__ Wm2, const float* __restrict__ bm2,
    float* __restrict__ logits, float* __restrict__ probs, float* __restrict__ lacc) {
  __shared__ char feat[128 * 512];  // 64 KB
  int t = threadIdx.x;
  int eb = blockIdx.x * 128;

  // stage: thread t fetches 256B node row for edge e = t>>1, half = t&1
  {
    int e = t >> 1, half = t & 1;
    int node = half ? ei[E_EDGES + eb + e] : ei[eb + e];
    const int4* src = (const int4*)(hb + (size_t)node * HID);
    int base = e * 512 + half * 256;
    int swz = (e & 7) << 4;
#pragma unroll
    for (int j = 0; j < 16; ++j) {
      int4 v = src[j];
      *(int4*)(feat + ((base + j * 16) ^ swz)) = v;
    }
  }
  __syncthreads();

  int wv = t >> 6, l = t & 63;
  int g = l >> 4, c0 = l & 15;
  int we = wv * 32;

  f32x4 acc[2][4];
#pragma unroll
  for (int i = 0; i < 2; ++i)
#pragma unroll
    for (int j = 0; j < 4; ++j) acc[i][j] = f32x4{0.f, 0.f, 0.f, 0.f};

#pragma unroll
  for (int kk = 0; kk < 8; ++kk) {
    int kb = kk * 64 + g * 16;          // byte offset along K for this lane
    int r0 = we + c0;
    int r1 = we + 16 + c0;
    bf16x8 a0 = *(const bf16x8*)(feat + ((r0 * 512 + kb) ^ ((r0 & 7) << 4)));
    bf16x8 a1 = *(const bf16x8*)(feat + ((r1 * 512 + kb) ^ ((r1 & 7) << 4)));
#pragma unroll
    for (int ct = 0; ct < 4; ++ct) {
      bf16x8 bf = *(const bf16x8*)(wb + (ct * 16 + c0) * 256 + kk * 32 + g * 8);
      acc[0][ct] = __builtin_amdgcn_mfma_f32_16x16x32_bf16(a0, bf, acc[0][ct], 0, 0, 0);
      acc[1][ct] = __builtin_amdgcn_mfma_f32_16x16x32_bf16(a1, bf, acc[1][ct], 0, 0, 0);
    }
  }

  // epilogue: fp32 second layer + softmax + loss
  float bmv[4], w0v[4], w1v[4], w2v[4];
#pragma unroll
  for (int ct = 0; ct < 4; ++ct) {
    int c = ct * 16 + c0;
    bmv[ct] = bm1[c];
    w0v[ct] = Wm2[c]; w1v[ct] = Wm2[64 + c]; w2v[ct] = Wm2[128 + c];
  }
  float bm20 = bm2[0], bm21 = bm2[1], bm22 = bm2[2];
  float kl = 0.f, rc = 0.f;

#pragma unroll
  for (int rt = 0; rt < 2; ++rt) {
    float p0[4], p1[4], p2[4];
#pragma unroll
    for (int reg = 0; reg < 4; ++reg) {
      float a = 0.f, b = 0.f, c = 0.f;
#pragma unroll
      for (int ct = 0; ct < 4; ++ct) {
        float hv = fmaxf(acc[rt][ct][reg] + bmv[ct], 0.f);
        a = fmaf(hv, w0v[ct], a);
        b = fmaf(hv, w1v[ct], b);
        c = fmaf(hv, w2v[ct], c);
      }
      p0[reg] = a; p1[reg] = b; p2[reg] = c;
    }
#pragma unroll
    for (int m = 1; m <= 8; m <<= 1) {
#pragma unroll
      for (int reg = 0; reg < 4; ++reg) {
        p0[reg] += __shfl_xor(p0[reg], m, 64);
        p1[reg] += __shfl_xor(p1[reg], m, 64);
        p2[reg] += __shfl_xor(p2[reg], m, 64);
      }
    }
    if (c0 < 4) {
      int reg = c0;
      int edge = eb + we + rt * 16 + g * 4 + reg;
      float l0 = p0[reg] + bm20, l1 = p1[reg] + bm21, l2 = p2[reg] + bm22;
      float mx = fmaxf(fmaxf(l0, l1), l2);
      float x0 = expf(l0 - mx), x1 = expf(l1 - mx), x2 = expf(l2 - mx);
      float inv = 1.f / (x0 + x1 + x2);
      float q0 = x0 * inv, q1 = x1 * inv, q2 = x2 * inv;
      logits[(size_t)edge * 3 + 0] = l0;
      logits[(size_t)edge * 3 + 1] = l1;
      logits[(size_t)edge * 3 + 2] = l2;
      probs[(size_t)edge * 3 + 0] = q0;
      probs[(size_t)edge * 3 + 1] = q1;
      probs[(size_t)edge * 3 + 2] = q2;
      float lp0 = logf(fmaxf(q0, 1e-12f));
      float lp1 = logf(fmaxf(q1, 1e-12f));
      float lp2 = logf(fmaxf(q2, 1e-12f));
      kl += q0 * (lp0 - PRIOR_LOG) + q1 * (lp1 - PRIOR_LOG) + q2 * (lp2 - PRIOR_LOG);
      rc += logf(fmaxf(q0 + q2, 1e-12f));
    }
  }
#pragma unroll
  for (int m = 1; m < 64; m <<= 1) {
    kl += __shfl_xor(kl, m, 64);
    rc += __shfl_xor(rc, m, 64);
  }
  if (l == 0) { atomicAdd(&lacc[0], kl); atomicAdd(&lacc[1], rc); }
}

__global__ void k_loss(const float* __restrict__ lacc, float* __restrict__ out) {
  if (threadIdx.x == 0) out[0] = (lacc[0] - lacc[1]) * (1.f / (float)E_EDGES);
}

// ---------------- launcher ----------------
extern "C" void kernel_launch(void* const* d_in, const int* in_sizes, int n_in,
                              void* d_out, int out_size, void* d_ws, size_t ws_size,
                              hipStream_t stream) {
  const float* x      = (const float*)d_in[0];
  const int*   ei     = (const int*)d_in[1];
  const int*   y      = (const int*)d_in[2];
  const int*   mask   = (const int*)d_in[3];
  const float* W1     = (const float*)d_in[4];
  const float* a_src1 = (const float*)d_in[5];
  const float* a_dst1 = (const float*)d_in[6];
  const float* b1     = (const float*)d_in[7];
  const float* W2     = (const float*)d_in[8];
  const float* a_src2 = (const float*)d_in[9];
  const float* a_dst2 = (const float*)d_in[10];
  const float* b2     = (const float*)d_in[11];
  const float* Wm1    = (const float*)d_in[12];
  const float* bm1    = (const float*)d_in[13];
  const float* Wm2    = (const float*)d_in[14];
  const float* bm2    = (const float*)d_in[15];

  float* A     = (float*)d_ws;            // hx / hx2      [N,128]
  float* Bb    = A + 6400000;             // out1 / out2   [N,128]
  float* as_   = Bb + 6400000;            // [N]
  float* ad_   = as_ + 50000;             // [N]
  unsigned* mkey = (unsigned*)(ad_ + 50000);  // [N]
  float* denom = (float*)(mkey + 50000);  // [N]
  float* ebuf  = denom + 50000;           // [E+N]
  float* W1T   = ebuf + 850000;           // [266*128]
  float* W2T   = W1T + 34048;             // [128*128]
  float* lacc  = W2T + 16384;             // [2]
  unsigned short* wb = (unsigned short*)(lacc + 2);   // Wm1 bf16 [64][256] = 32 KB
  unsigned short* hb = (unsigned short*)A;            // h bf16, aliases A (dead by then)

  k_transpose<<<(HID * FEAT_IN + 255) / 256, 256, 0, stream>>>(W1, W1T, HID, FEAT_IN);
  k_transpose<<<(HID * HID + 255) / 256, 256, 0, stream>>>(W2, W2T, HID, HID);
  k_cvtw<<<(EHID * 2 * HID + 255) / 256, 256, 0, stream>>>(Wm1, wb, EHID * 2 * HID);

  const int EB = (E_EDGES + N_NODES + 255) / 256;

  // ---- layer 1 ----
  k_gemm1<<<(N_NODES + 31) / 32, 256, 0, stream>>>(x, y, mask, W1T, A);
  k_alpha<<<(N_NODES + 3) / 4, 256, 0, stream>>>(A, a_src1, a_dst1, as_, ad_);
  hipMemsetAsync(mkey, 0, 100000 * 4, stream);      // mkey + denom (adjacent)
  hipMemsetAsync(Bb, 0, 6400000 * 4, stream);
  hipMemsetAsync(lacc, 0, 2 * 4, stream);
  k_edge_max<<<EB, 256, 0, stream>>>(ei, as_, ad_, ebuf, mkey);
  k_edge_exp<<<EB, 256, 0, stream>>>(ei, ebuf, mkey, denom);
  k_scatter<<<(E_EDGES + N_NODES + 3) / 4, 256, 0, stream>>>(ei, ebuf, denom, A, Bb);

  // ---- layer 2 ----
  k_gemm2<<<(N_NODES + 63) / 64, 256, 0, stream>>>(Bb, b1, W2T, A);
  k_fillb2<<<(N_NODES * HID + 255) / 256, 256, 0, stream>>>(b2, Bb);  // pre-fill with b2
  k_alpha<<<(N_NODES + 3) / 4, 256, 0, stream>>>(A, a_src2, a_dst2, as_, ad_);
  hipMemsetAsync(mkey, 0, 100000 * 4, stream);
  k_edge_max<<<EB, 256, 0, stream>>>(ei, as_, ad_, ebuf, mkey);
  k_edge_exp<<<EB, 256, 0, stream>>>(ei, ebuf, mkey, denom);
  k_scatter<<<(E_EDGES + N_NODES + 3) / 4, 256, 0, stream>>>(ei, ebuf, denom, A, Bb);

  // ---- edge MLP (bf16 MFMA) + loss ----
  k_tobf16<<<(N_NODES * HID + 255) / 256, 256, 0, stream>>>(Bb, hb);  // hb aliases A (A dead)
  float* logits = (float*)d_out;
  float* probs  = logits + 2400000;
  float* lossp  = logits + 4800000;
  k_mlp_mfma<<<E_EDGES / 128, 256, 0, stream>>>(ei, hb, wb, bm1, Wm2, bm2,
                                                logits, probs, lacc);
  k_loss<<<1, 64, 0, stream>>>(lacc, lossp);
}

// Round 3
// 1624.941 us; speedup vs baseline: 2.0410x; 1.1630x over previous
//
#include <hip/hip_runtime.h>
#include <hip/hip_bf16.h>

#define N_NODES 50000
#define E_EDGES 800000
#define IN_DIM  256
#define HID     128
#define FEAT_IN 266
#define EHID    64
#define NEG     0.2f
#define PRIOR_LOG (-1.0986122886681098f)  // log(1/3 + 1e-12)
#define NB_SCAN 196                        // ceil(50000/256)

typedef short bf16x8 __attribute__((ext_vector_type(8)));
typedef float f32x4 __attribute__((ext_vector_type(4)));

__device__ __forceinline__ unsigned short f2bf(float f) {
  unsigned u = __float_as_uint(f);
  u += 0x7fffu + ((u >> 16) & 1u);   // round-to-nearest-even
  return (unsigned short)(u >> 16);
}

// ---------------- weight transpose: W[R][C] -> WT[C][R] ----------------
__global__ void k_transpose(const float* __restrict__ W, float* __restrict__ WT, int R, int C) {
  int i = blockIdx.x * 256 + threadIdx.x;
  if (i < R * C) {
    int r = i / C, c = i - r * C;
    WT[c * R + r] = W[i];
  }
}

// ---------------- CSR build ----------------
__global__ void k_deg(const int* __restrict__ ei, int* __restrict__ deg) {
  int e = blockIdx.x * 256 + threadIdx.x;
  if (e < E_EDGES) atomicAdd(&deg[ei[E_EDGES + e]], 1);
}

__global__ void k_scan1(const int* __restrict__ deg, int* __restrict__ rowptr,
                        int* __restrict__ bsum) {
  __shared__ int sh[256];
  int t = threadIdx.x, i = blockIdx.x * 256 + t;
  int v = (i < N_NODES) ? deg[i] : 0;
  sh[t] = v;
  __syncthreads();
  for (int off = 1; off < 256; off <<= 1) {
    int x = (t >= off) ? sh[t - off] : 0;
    __syncthreads();
    sh[t] += x;
    __syncthreads();
  }
  if (i < N_NODES) rowptr[i] = sh[t] - v;   // exclusive within chunk
  if (t == 255) bsum[blockIdx.x] = sh[255];
}

__global__ void k_scan2(const int* __restrict__ bsum, int* __restrict__ boff,
                        int* __restrict__ rowptr) {
  __shared__ int sh[256];
  int t = threadIdx.x;
  int v = (t < NB_SCAN) ? bsum[t] : 0;
  sh[t] = v;
  __syncthreads();
  for (int off = 1; off < 256; off <<= 1) {
    int x = (t >= off) ? sh[t - off] : 0;
    __syncthreads();
    sh[t] += x;
    __syncthreads();
  }
  if (t < NB_SCAN) boff[t] = sh[t] - v;
  if (t == NB_SCAN - 1) rowptr[N_NODES] = sh[t];   // total = E
}

__global__ void k_scan3(int* __restrict__ rowptr, const int* __restrict__ boff) {
  int i = blockIdx.x * 256 + threadIdx.x;
  if (i < N_NODES) rowptr[i] += boff[i >> 8];
}

__global__ void k_fill(const int* __restrict__ ei, const int* __restrict__ rowptr,
                       int* __restrict__ fill, int* __restrict__ cols) {
  int e = blockIdx.x * 256 + threadIdx.x;
  if (e < E_EDGES) {
    int d = ei[E_EDGES + e];
    int slot = atomicAdd(&fill[d], 1);
    cols[rowptr[d] + slot] = ei[e];
  }
}

// ---------------- GEMM1: hx = [x | onehot(y)*mask] @ W1^T ----------------
__global__ __launch_bounds__(256) void k_gemm1(
    const float* __restrict__ x, const int* __restrict__ y, const int* __restrict__ mask,
    const float* __restrict__ W1T, float* __restrict__ hx) {
  __shared__ float xs[32][268];
  int b0 = blockIdx.x * 32;
  int t = threadIdx.x;
  {
    int c4 = t & 63, rb = t >> 6;
    for (int i = 0; i < 8; ++i) {
      int r = rb * 8 + i;
      int row = b0 + r;
      float4 v = make_float4(0.f, 0.f, 0.f, 0.f);
      if (row < N_NODES) v = *(const float4*)&x[(size_t)row * IN_DIM + c4 * 4];
      *(float4*)&xs[r][c4 * 4] = v;
    }
  }
  for (int s = t; s < 32 * 12; s += 256) {
    int r = s / 12, c = s - r * 12;
    int row = b0 + r;
    float v = 0.f;
    if (c < 10 && row < N_NODES)
      v = (mask[row] != 0 && y[row] == c) ? 1.f : 0.f;
    xs[r][256 + c] = v;
  }
  __syncthreads();

  int lane = t & 63, wv = t >> 6;
  int r0 = wv * 8;
  int k0 = lane, k1 = lane + 64;
  float acc0[8], acc1[8];
#pragma unroll
  for (int i = 0; i < 8; ++i) { acc0[i] = 0.f; acc1[i] = 0.f; }

  for (int f = 0; f < 264; f += 4) {
    float wa0 = W1T[(f + 0) * HID + k0], wb0 = W1T[(f + 0) * HID + k1];
    float wa1 = W1T[(f + 1) * HID + k0], wb1 = W1T[(f + 1) * HID + k1];
    float wa2 = W1T[(f + 2) * HID + k0], wb2 = W1T[(f + 2) * HID + k1];
    float wa3 = W1T[(f + 3) * HID + k0], wb3 = W1T[(f + 3) * HID + k1];
#pragma unroll
    for (int i = 0; i < 8; ++i) {
      float4 xv = *(float4*)&xs[r0 + i][f];
      float a = acc0[i], b = acc1[i];
      a = fmaf(xv.x, wa0, a); b = fmaf(xv.x, wb0, b);
      a = fmaf(xv.y, wa1, a); b = fmaf(xv.y, wb1, b);
      a = fmaf(xv.z, wa2, a); b = fmaf(xv.z, wb2, b);
      a = fmaf(xv.w, wa3, a); b = fmaf(xv.w, wb3, b);
      acc0[i] = a; acc1[i] = b;
    }
  }
  for (int f = 264; f < 266; ++f) {
    float wa = W1T[f * HID + k0], wb = W1T[f * HID + k1];
#pragma unroll
    for (int i = 0; i < 8; ++i) {
      float xv = xs[r0 + i][f];
      acc0[i] = fmaf(xv, wa, acc0[i]);
      acc1[i] = fmaf(xv, wb, acc1[i]);
    }
  }
#pragma unroll
  for (int i = 0; i < 8; ++i) {
    int row = b0 + r0 + i;
    if (row < N_NODES) {
      hx[(size_t)row * HID + k0] = acc0[i];
      hx[(size_t)row * HID + k1] = acc1[i];
    }
  }
}

// ---------------- GEMM2: hx2 = relu(in + b1) @ W2^T ----------------
__global__ __launch_bounds__(256) void k_gemm2(
    const float* __restrict__ in, const float* __restrict__ b1,
    const float* __restrict__ W2T, float* __restrict__ hx) {
  __shared__ float xs[64][128];
  int b0 = blockIdx.x * 64;
  int t = threadIdx.x;
  {
    int c4 = t & 31, rb = t >> 5;
    for (int i = 0; i < 8; ++i) {
      int r = rb * 8 + i;
      int row = b0 + r;
      float4 v = make_float4(0.f, 0.f, 0.f, 0.f);
      if (row < N_NODES) {
        v = *(const float4*)&in[(size_t)row * HID + c4 * 4];
        float4 bb = *(const float4*)&b1[c4 * 4];
        v.x = fmaxf(v.x + bb.x, 0.f); v.y = fmaxf(v.y + bb.y, 0.f);
        v.z = fmaxf(v.z + bb.z, 0.f); v.w = fmaxf(v.w + bb.w, 0.f);
      }
      *(float4*)&xs[r][c4 * 4] = v;
    }
  }
  __syncthreads();

  int lane = t & 63, wv = t >> 6;
  int r0 = wv * 16;
  int k0 = lane, k1 = lane + 64;
  float acc0[16], acc1[16];
#pragma unroll
  for (int i = 0; i < 16; ++i) { acc0[i] = 0.f; acc1[i] = 0.f; }

  for (int f = 0; f < 128; f += 4) {
    float wa0 = W2T[(f + 0) * HID + k0], wb0 = W2T[(f + 0) * HID + k1];
    float wa1 = W2T[(f + 1) * HID + k0], wb1 = W2T[(f + 1) * HID + k1];
    float wa2 = W2T[(f + 2) * HID + k0], wb2 = W2T[(f + 2) * HID + k1];
    float wa3 = W2T[(f + 3) * HID + k0], wb3 = W2T[(f + 3) * HID + k1];
#pragma unroll
    for (int i = 0; i < 16; ++i) {
      float4 xv = *(float4*)&xs[r0 + i][f];
      float a = acc0[i], b = acc1[i];
      a = fmaf(xv.x, wa0, a); b = fmaf(xv.x, wb0, b);
      a = fmaf(xv.y, wa1, a); b = fmaf(xv.y, wb1, b);
      a = fmaf(xv.z, wa2, a); b = fmaf(xv.z, wb2, b);
      a = fmaf(xv.w, wa3, a); b = fmaf(xv.w, wb3, b);
      acc0[i] = a; acc1[i] = b;
    }
  }
#pragma unroll
  for (int i = 0; i < 16; ++i) {
    int row = b0 + r0 + i;
    if (row < N_NODES) {
      hx[(size_t)row * HID + k0] = acc0[i];
      hx[(size_t)row * HID + k1] = acc1[i];
    }
  }
}

// ---------------- alpha_s / alpha_d ----------------
__global__ __launch_bounds__(256) void k_alpha(
    const float* __restrict__ hx, const float* __restrict__ a_s, const float* __restrict__ a_d,
    float* __restrict__ as_, float* __restrict__ ad_) {
  int gw = (blockIdx.x * 256 + threadIdx.x) >> 6;
  int lane = threadIdx.x & 63;
  if (gw >= N_NODES) return;
  float h0 = hx[(size_t)gw * HID + lane], h1 = hx[(size_t)gw * HID + 64 + lane];
  float ps = h0 * a_s[lane] + h1 * a_s[64 + lane];
  float pd = h0 * a_d[lane] + h1 * a_d[64 + lane];
#pragma unroll
  for (int m = 32; m; m >>= 1) {
    ps += __shfl_xor(ps, m, 64);
    pd += __shfl_xor(pd, m, 64);
  }
  if (lane == 0) { as_[gw] = ps; ad_[gw] = pd; }
}

// ---------------- fused GAT aggregation: wave per node, online softmax ----------------
// BF16OUT=0: out_f32[n] = agg ; BF16OUT=1: out_bf16[n] = bf16(agg + b2)
template <int BF16OUT>
__global__ __launch_bounds__(256) void k_aggr(
    const int* __restrict__ rowptr, const int* __restrict__ cols,
    const float* __restrict__ as_, const float* __restrict__ ad_,
    const float* __restrict__ h, float* __restrict__ outf,
    unsigned short* __restrict__ outb, const float* __restrict__ b2) {
  int n = (blockIdx.x * 256 + threadIdx.x) >> 6;
  int l = threadIdx.x & 63;
  if (n >= N_NODES) return;
  int base = rowptr[n], end = rowptr[n + 1];
  float adn = ad_[n];
  float m = -1e30f, ssum = 0.f, acc0 = 0.f, acc1 = 0.f;

  for (int c = base; c < end; c += 64) {
    int idx = c + l;
    bool valid = idx < end;
    int col = valid ? cols[idx] : 0;
    float raw = as_[col] + adn;
    float lr = raw > 0.f ? raw : NEG * raw;
    float e = valid ? lr : -1e30f;
    float cm = e;
#pragma unroll
    for (int s = 32; s; s >>= 1) cm = fmaxf(cm, __shfl_xor(cm, s, 64));
    float mn = fmaxf(m, cm);
    float scale = expf(m - mn);
    ssum *= scale; acc0 *= scale; acc1 *= scale;
    m = mn;
    float p = expf(e - m);          // invalid lanes -> 0
    float cs = p;
#pragma unroll
    for (int s = 32; s; s >>= 1) cs += __shfl_xor(cs, s, 64);
    ssum += cs;
    int cnt = end - c; if (cnt > 64) cnt = 64;
    for (int j = 0; j < cnt; ++j) {
      float pj = __shfl(p, j, 64);
      int cj = __shfl(col, j, 64);
      acc0 = fmaf(pj, h[(size_t)cj * HID + l], acc0);
      acc1 = fmaf(pj, h[(size_t)cj * HID + 64 + l], acc1);
    }
  }
  // self loop
  float raw = as_[n] + adn;
  float es = raw > 0.f ? raw : NEG * raw;
  float mn = fmaxf(m, es);
  float scale = expf(m - mn);
  ssum *= scale; acc0 *= scale; acc1 *= scale;
  float ps = expf(es - mn);
  ssum += ps;
  acc0 = fmaf(ps, h[(size_t)n * HID + l], acc0);
  acc1 = fmaf(ps, h[(size_t)n * HID + 64 + l], acc1);

  float inv = 1.f / ssum;
  if (BF16OUT) {
    outb[(size_t)n * HID + l]      = f2bf(acc0 * inv + b2[l]);
    outb[(size_t)n * HID + 64 + l] = f2bf(acc1 * inv + b2[64 + l]);
  } else {
    outf[(size_t)n * HID + l]      = acc0 * inv;
    outf[(size_t)n * HID + 64 + l] = acc1 * inv;
  }
}

// ---------------- fp32 -> bf16 weight conversion ----------------
__global__ void k_cvtw(const float* __restrict__ in, unsigned short* __restrict__ out, int n) {
  int i = blockIdx.x * 256 + threadIdx.x;
  if (i < n) out[i] = f2bf(in[i]);
}

// ---------------- edge MLP via bf16 MFMA, A gathered direct from global ----------------
// 256 thr = 4 waves; wave = 32 edges (two 16-row MFMA tiles); no LDS
__global__ __launch_bounds__(256) void k_mlp_mfma(
    const int* __restrict__ ei, const unsigned short* __restrict__ hb,
    const unsigned short* __restrict__ wb, const float* __restrict__ bm1,
    const float* __restrict__ Wm2, const float* __restrict__ bm2,
    float* __restrict__ logits, float* __restrict__ probs, float* __restrict__ lacc) {
  int t = threadIdx.x;
  int wv = t >> 6, l = t & 63;
  int g = l >> 4, c0 = l & 15;
  int eb = blockIdx.x * 128 + wv * 32;    // wave's 32-edge base

  int e0 = eb + c0, e1 = eb + 16 + c0;
  int s0 = ei[e0], d0 = ei[E_EDGES + e0];
  int s1 = ei[e1], d1 = ei[E_EDGES + e1];
  const bf16x8* ps0 = (const bf16x8*)(hb + (size_t)s0 * HID);
  const bf16x8* pd0 = (const bf16x8*)(hb + (size_t)d0 * HID);
  const bf16x8* ps1 = (const bf16x8*)(hb + (size_t)s1 * HID);
  const bf16x8* pd1 = (const bf16x8*)(hb + (size_t)d1 * HID);

  // A fragments: lane (c0,g) needs elems [kk*32 + g*8, +8) of the 256-elem edge row
  bf16x8 a0f[8], a1f[8];
#pragma unroll
  for (int kk = 0; kk < 4; ++kk) {
    a0f[kk]     = ps0[kk * 4 + g];
    a1f[kk]     = ps1[kk * 4 + g];
    a0f[4 + kk] = pd0[kk * 4 + g];
    a1f[4 + kk] = pd1[kk * 4 + g];
  }

  f32x4 acc[2][4];
#pragma unroll
  for (int i = 0; i < 2; ++i)
#pragma unroll
    for (int j = 0; j < 4; ++j) acc[i][j] = f32x4{0.f, 0.f, 0.f, 0.f};

#pragma unroll
  for (int kk = 0; kk < 8; ++kk) {
#pragma unroll
    for (int ct = 0; ct < 4; ++ct) {
      bf16x8 bf = *(const bf16x8*)(wb + (ct * 16 + c0) * 256 + kk * 32 + g * 8);
      acc[0][ct] = __builtin_amdgcn_mfma_f32_16x16x32_bf16(a0f[kk], bf, acc[0][ct], 0, 0, 0);
      acc[1][ct] = __builtin_amdgcn_mfma_f32_16x16x32_bf16(a1f[kk], bf, acc[1][ct], 0, 0, 0);
    }
  }

  // epilogue: fp32 second layer + softmax + loss
  float bmv[4], w0v[4], w1v[4], w2v[4];
#pragma unroll
  for (int ct = 0; ct < 4; ++ct) {
    int c = ct * 16 + c0;
    bmv[ct] = bm1[c];
    w0v[ct] = Wm2[c]; w1v[ct] = Wm2[64 + c]; w2v[ct] = Wm2[128 + c];
  }
  float bm20 = bm2[0], bm21 = bm2[1], bm22 = bm2[2];
  float kl = 0.f, rc = 0.f;

#pragma unroll
  for (int rt = 0; rt < 2; ++rt) {
    float p0[4], p1[4], p2[4];
#pragma unroll
    for (int reg = 0; reg < 4; ++reg) {
      float a = 0.f, b = 0.f, c = 0.f;
#pragma unroll
      for (int ct = 0; ct < 4; ++ct) {
        float hv = fmaxf(acc[rt][ct][reg] + bmv[ct], 0.f);
        a = fmaf(hv, w0v[ct], a);
        b = fmaf(hv, w1v[ct], b);
        c = fmaf(hv, w2v[ct], c);
      }
      p0[reg] = a; p1[reg] = b; p2[reg] = c;
    }
#pragma unroll
    for (int m = 1; m <= 8; m <<= 1) {
#pragma unroll
      for (int reg = 0; reg < 4; ++reg) {
        p0[reg] += __shfl_xor(p0[reg], m, 64);
        p1[reg] += __shfl_xor(p1[reg], m, 64);
        p2[reg] += __shfl_xor(p2[reg], m, 64);
      }
    }
    if (c0 < 4) {
      int reg = c0;
      int edge = eb + rt * 16 + g * 4 + reg;
      float l0 = p0[reg] + bm20, l1 = p1[reg] + bm21, l2 = p2[reg] + bm22;
      float mx = fmaxf(fmaxf(l0, l1), l2);
      float x0 = expf(l0 - mx), x1 = expf(l1 - mx), x2 = expf(l2 - mx);
      float inv = 1.f / (x0 + x1 + x2);
      float q0 = x0 * inv, q1 = x1 * inv, q2 = x2 * inv;
      logits[(size_t)edge * 3 + 0] = l0;
      logits[(size_t)edge * 3 + 1] = l1;
      logits[(size_t)edge * 3 + 2] = l2;
      probs[(size_t)edge * 3 + 0] = q0;
      probs[(size_t)edge * 3 + 1] = q1;
      probs[(size_t)edge * 3 + 2] = q2;
      float lp0 = logf(fmaxf(q0, 1e-12f));
      float lp1 = logf(fmaxf(q1, 1e-12f));
      float lp2 = logf(fmaxf(q2, 1e-12f));
      kl += q0 * (lp0 - PRIOR_LOG) + q1 * (lp1 - PRIOR_LOG) + q2 * (lp2 - PRIOR_LOG);
      rc += logf(fmaxf(q0 + q2, 1e-12f));
    }
  }
#pragma unroll
  for (int m = 1; m < 64; m <<= 1) {
    kl += __shfl_xor(kl, m, 64);
    rc += __shfl_xor(rc, m, 64);
  }
  if (l == 0) { atomicAdd(&lacc[0], kl); atomicAdd(&lacc[1], rc); }
}

__global__ void k_loss(const float* __restrict__ lacc, float* __restrict__ out) {
  if (threadIdx.x == 0) out[0] = (lacc[0] - lacc[1]) * (1.f / (float)E_EDGES);
}

// ---------------- launcher ----------------
extern "C" void kernel_launch(void* const* d_in, const int* in_sizes, int n_in,
                              void* d_out, int out_size, void* d_ws, size_t ws_size,
                              hipStream_t stream) {
  const float* x      = (const float*)d_in[0];
  const int*   ei     = (const int*)d_in[1];
  const int*   y      = (const int*)d_in[2];
  const int*   mask   = (const int*)d_in[3];
  const float* W1     = (const float*)d_in[4];
  const float* a_src1 = (const float*)d_in[5];
  const float* a_dst1 = (const float*)d_in[6];
  const float* b1     = (const float*)d_in[7];
  const float* W2     = (const float*)d_in[8];
  const float* a_src2 = (const float*)d_in[9];
  const float* a_dst2 = (const float*)d_in[10];
  const float* b2     = (const float*)d_in[11];
  const float* Wm1    = (const float*)d_in[12];
  const float* bm1    = (const float*)d_in[13];
  const float* Wm2    = (const float*)d_in[14];
  const float* bm2    = (const float*)d_in[15];

  float* A      = (float*)d_ws;                 // hx / hx2  [N,128]
  float* Bb     = A + 6400000;                  // agg1      [N,128]
  float* as_    = Bb + 6400000;                 // [N]
  float* ad_    = as_ + 50000;                  // [N]
  int*   deg    = (int*)(ad_ + 50000);          // [N]
  int*   fill   = deg + 50000;                  // [N]
  int*   rowptr = fill + 50000;                 // [N+1]
  int*   bsum   = rowptr + 50001;               // [256]
  int*   boff   = bsum + 256;                   // [256]
  int*   cols   = boff + 256;                   // [E]
  float* W1T    = (float*)(cols + 800000);      // [266*128]
  float* W2T    = W1T + 34048;                  // [128*128]
  float* lacc   = W2T + 16384;                  // [2]
  unsigned short* wb = (unsigned short*)(lacc + 2);  // Wm1 bf16 [64][256]
  unsigned short* hb = (unsigned short*)Bb;     // layer-2 agg bf16 (aliases Bb, dead)

  const int EBLK = (E_EDGES + 255) / 256;

  // ---- CSR build (graph fixed; reused by both layers) ----
  hipMemsetAsync(deg, 0, 50000 * 4, stream);
  hipMemsetAsync(fill, 0, 50000 * 4, stream);
  hipMemsetAsync(lacc, 0, 2 * 4, stream);
  k_deg<<<EBLK, 256, 0, stream>>>(ei, deg);
  k_scan1<<<NB_SCAN, 256, 0, stream>>>(deg, rowptr, bsum);
  k_scan2<<<1, 256, 0, stream>>>(bsum, boff, rowptr);
  k_scan3<<<NB_SCAN, 256, 0, stream>>>(rowptr, boff);
  k_fill<<<EBLK, 256, 0, stream>>>(ei, rowptr, fill, cols);

  // ---- weight prep ----
  k_transpose<<<(HID * FEAT_IN + 255) / 256, 256, 0, stream>>>(W1, W1T, HID, FEAT_IN);
  k_transpose<<<(HID * HID + 255) / 256, 256, 0, stream>>>(W2, W2T, HID, HID);
  k_cvtw<<<(EHID * 2 * HID + 255) / 256, 256, 0, stream>>>(Wm1, wb, EHID * 2 * HID);

  // ---- layer 1 ----
  k_gemm1<<<(N_NODES + 31) / 32, 256, 0, stream>>>(x, y, mask, W1T, A);
  k_alpha<<<(N_NODES + 3) / 4, 256, 0, stream>>>(A, a_src1, a_dst1, as_, ad_);
  k_aggr<0><<<(N_NODES + 3) / 4, 256, 0, stream>>>(rowptr, cols, as_, ad_, A, Bb, nullptr, nullptr);

  // ---- layer 2 ----
  k_gemm2<<<(N_NODES + 63) / 64, 256, 0, stream>>>(Bb, b1, W2T, A);
  k_alpha<<<(N_NODES + 3) / 4, 256, 0, stream>>>(A, a_src2, a_dst2, as_, ad_);
  k_aggr<1><<<(N_NODES + 3) / 4, 256, 0, stream>>>(rowptr, cols, as_, ad_, A, nullptr, hb, b2);

  // ---- edge MLP (bf16 MFMA, direct-global gather) + loss ----
  float* logits = (float*)d_out;
  float* probs  = logits + 2400000;
  float* lossp  = logits + 4800000;
  k_mlp_mfma<<<E_EDGES / 128, 256, 0, stream>>>(ei, hb, wb, bm1, Wm2, bm2,
                                                logits, probs, lacc);
  k_loss<<<1, 64, 0, stream>>>(lacc, lossp);
}